// Round 5
// baseline (405.521 us; speedup 1.0000x reference)
//
#include <hip/hip_runtime.h>

// SCELoss: pred [N=8, C=19, H=512, W=1024] fp32, labels [8,512,1024] int32 (255 = ignore)
// out = 0.1 * CE + 1.0 * RCE_mean, scalar fp32.
//
// R5: R4 + __launch_bounds__(256, 8). R4's -10us from pure-VALU reduction
// proved compute is NOT hidden under memory -> low occupancy (compiler
// hoists all 19 loads, ~100+ VGPR, ~4 waves/SIMD). Cap to 64 VGPR ->
// 8 waves/SIMD so vmcnt waits are covered by other waves; the register cap
// also bounds the compiler's load-hoist window to a sane ~6-8 in flight
// (still far above the ~2.3 KB/SIMD needed to hide HBM latency).

#define NCLS 19
#define HW (512 * 1024)        // 2^19
#define NPIX (8 * HW)          // 4,194,304 pixels
#define IGNORE_L 255
#define GRID_MAIN 4096         // (NPIX/4) / 256

typedef float f32x4 __attribute__((ext_vector_type(4)));
typedef int   i32x4 __attribute__((ext_vector_type(4)));

static constexpr float NEG_LOG_OH = 9.210340371976184f;  // -log(1e-4)
static constexpr float P_MIN_F = 1e-7f;

__global__ __launch_bounds__(256, 8) void sce_main(const float* __restrict__ pred,
                                                   const int* __restrict__ labels,
                                                   float* __restrict__ ws) {
    const int t = blockIdx.x * 256 + threadIdx.x;
    const int p0 = t * 4;  // 4 consecutive pixels per thread

    const int n = p0 >> 19;           // batch index (HW = 2^19)
    const int hw = p0 & (HW - 1);
    const float* base = pred + ((size_t)n * NCLS) * (size_t)HW + (size_t)hw;

    const i32x4 labv = __builtin_nontemporal_load((const i32x4*)(labels + p0));

    // Four independent accumulation chains (ILP); loads pipelined by compiler
    // within the 64-VGPR budget.
    float s0 = 0.0f, s1 = 0.0f, s2 = 0.0f, s3 = 0.0f;
    float xy0 = 0.0f, xy1 = 0.0f, xy2 = 0.0f, xy3 = 0.0f;
    #pragma unroll
    for (int c = 0; c < NCLS; ++c) {
        const f32x4 v = __builtin_nontemporal_load((const f32x4*)(base + (size_t)c * HW));
        s0 += __expf(v.x); if (labv.x == c) xy0 = v.x;
        s1 += __expf(v.y); if (labv.y == c) xy1 = v.y;
        s2 += __expf(v.z); if (labv.z == c) xy2 = v.z;
        s3 += __expf(v.w); if (labv.w == c) xy3 = v.w;
    }

    float ce_acc = 0.0f, rce_acc = 0.0f, cnt = 0.0f;
    {
        const float py0 = fminf(fmaxf(__expf(xy0) / s0, P_MIN_F), 1.0f);
        const float py1 = fminf(fmaxf(__expf(xy1) / s1, P_MIN_F), 1.0f);
        const float py2 = fminf(fmaxf(__expf(xy2) / s2, P_MIN_F), 1.0f);
        const float py3 = fminf(fmaxf(__expf(xy3) / s3, P_MIN_F), 1.0f);
        if (labv.x != IGNORE_L) { ce_acc += __logf(s0) - xy0; rce_acc += 1.0f - py0; cnt += 1.0f; }
        if (labv.y != IGNORE_L) { ce_acc += __logf(s1) - xy1; rce_acc += 1.0f - py1; cnt += 1.0f; }
        if (labv.z != IGNORE_L) { ce_acc += __logf(s2) - xy2; rce_acc += 1.0f - py2; cnt += 1.0f; }
        if (labv.w != IGNORE_L) { ce_acc += __logf(s3) - xy3; rce_acc += 1.0f - py3; cnt += 1.0f; }
    }

    // Wave-64 reduction.
    #pragma unroll
    for (int off = 32; off > 0; off >>= 1) {
        ce_acc  += __shfl_down(ce_acc, off);
        rce_acc += __shfl_down(rce_acc, off);
        cnt     += __shfl_down(cnt, off);
    }

    // Block reduction (4 waves), per-block partial write (no atomics).
    __shared__ float red_ce[4], red_rce[4], red_cnt[4];
    const int wave = threadIdx.x >> 6;
    const int lane = threadIdx.x & 63;
    if (lane == 0) { red_ce[wave] = ce_acc; red_rce[wave] = rce_acc; red_cnt[wave] = cnt; }
    __syncthreads();
    if (threadIdx.x == 0) {
        const int b = blockIdx.x;
        ws[b]               = red_ce[0] + red_ce[1] + red_ce[2] + red_ce[3];
        ws[GRID_MAIN + b]   = red_rce[0] + red_rce[1] + red_rce[2] + red_rce[3];
        ws[2*GRID_MAIN + b] = red_cnt[0] + red_cnt[1] + red_cnt[2] + red_cnt[3];
    }
}

__global__ __launch_bounds__(256) void sce_finalize(const float* __restrict__ ws,
                                                    float* __restrict__ out) {
    float ce = 0.0f, rce = 0.0f, cnt = 0.0f;
    for (int i = threadIdx.x; i < GRID_MAIN; i += 256) {
        ce  += ws[i];
        rce += ws[GRID_MAIN + i];
        cnt += ws[2*GRID_MAIN + i];
    }
    #pragma unroll
    for (int off = 32; off > 0; off >>= 1) {
        ce  += __shfl_down(ce, off);
        rce += __shfl_down(rce, off);
        cnt += __shfl_down(cnt, off);
    }
    __shared__ float red_ce[4], red_rce[4], red_cnt[4];
    const int wave = threadIdx.x >> 6;
    const int lane = threadIdx.x & 63;
    if (lane == 0) { red_ce[wave] = ce; red_rce[wave] = rce; red_cnt[wave] = cnt; }
    __syncthreads();
    if (threadIdx.x == 0) {
        const float tce  = red_ce[0] + red_ce[1] + red_ce[2] + red_ce[3];
        const float trce = red_rce[0] + red_rce[1] + red_rce[2] + red_rce[3];
        const float tcnt = red_cnt[0] + red_cnt[1] + red_cnt[2] + red_cnt[3];
        out[0] = 0.1f * (tce / tcnt) + NEG_LOG_OH * (trce / tcnt);
    }
}

extern "C" void kernel_launch(void* const* d_in, const int* in_sizes, int n_in,
                              void* d_out, int out_size, void* d_ws, size_t ws_size,
                              hipStream_t stream) {
    const float* pred = (const float*)d_in[0];
    const int* labels = (const int*)d_in[1];
    float* ws = (float*)d_ws;
    float* out = (float*)d_out;

    sce_main<<<GRID_MAIN, 256, 0, stream>>>(pred, labels, ws);
    sce_finalize<<<1, 256, 0, stream>>>(ws, out);
}